// Round 4
// baseline (13433.105 us; speedup 1.0000x reference)
//
#include <hip/hip_runtime.h>
#include <hip/hip_fp16.h>
#include <math.h>

#define L_SEQ 4096
#define H_DIM 512
#define M_DIM 1024
#define G4    2048   // 4*H
#define N_WG  32
#define CHUNK 16     // h indices per workgroup

#define OUT_HT 0
#define OUT_CT 512
#define OUT_Y  1024
#define OUT_A  (1024 + L_SEQ*H_DIM)   // 2098176

typedef unsigned long long ull;

__device__ __forceinline__ float fast_sigmoid(float v) {
    return 1.0f / (1.0f + __expf(-v));
}
__device__ __forceinline__ float fast_tanh(float v) {
    const float ax = fabsf(v);
    const float e = __expf(2.0f * ax);          // inf for large ax -> r = 1
    const float r = 1.0f - 2.0f / (e + 1.0f);
    return copysignf(r, v);
}

// ---------------------------------------------------------------------------
// x[l, :] = embed[sent[l], :]
// ---------------------------------------------------------------------------
__global__ void gather_embed(const int* __restrict__ sent,
                             const float* __restrict__ embed,
                             float* __restrict__ x) {
    const int l = blockIdx.x;
    const int t = threadIdx.x;          // 128 threads, float4 each
    const int row = sent[l];
    const float4 v = *(const float4*)&embed[(size_t)row * H_DIM + t * 4];
    *(float4*)&x[(size_t)l * H_DIM + t * 4] = v;
}

// ---------------------------------------------------------------------------
// Generic fp32 tile GEMM (64x64 tile, BK=16, 256 thr, 4x4 micro) — unchanged.
// ---------------------------------------------------------------------------
template<bool AT, bool BT, bool ADD_C, bool BIAS>
__global__ __launch_bounds__(256) void gemm_tile(
    const float* __restrict__ A, int lda,
    const float* __restrict__ B, int ldb,
    float* __restrict__ C, int ldc,
    int K,
    const float* __restrict__ bias1,
    const float* __restrict__ bias2) {

    __shared__ float sA[16][68];
    __shared__ float sB[16][68];

    const int tid = threadIdx.x;
    const int i0 = blockIdx.y * 64;
    const int j0 = blockIdx.x * 64;
    const int ti = tid & 15;
    const int tj = tid >> 4;

    float acc[4][4] = {};

    for (int k0 = 0; k0 < K; k0 += 16) {
        if (!AT) {
            const int row = tid >> 2, kq = tid & 3;
            const float4 v = *(const float4*)&A[(size_t)(i0 + row) * lda + k0 + kq * 4];
            sA[kq * 4 + 0][row] = v.x;
            sA[kq * 4 + 1][row] = v.y;
            sA[kq * 4 + 2][row] = v.z;
            sA[kq * 4 + 3][row] = v.w;
        } else {
            const int krow = tid >> 4, ic = tid & 15;
            const float4 v = *(const float4*)&A[(size_t)(k0 + krow) * lda + i0 + ic * 4];
            *(float4*)&sA[krow][ic * 4] = v;
        }
        if (BT) {
            const int row = tid >> 2, kq = tid & 3;
            const float4 v = *(const float4*)&B[(size_t)(j0 + row) * ldb + k0 + kq * 4];
            sB[kq * 4 + 0][row] = v.x;
            sB[kq * 4 + 1][row] = v.y;
            sB[kq * 4 + 2][row] = v.z;
            sB[kq * 4 + 3][row] = v.w;
        } else {
            const int krow = tid >> 4, jc = tid & 15;
            const float4 v = *(const float4*)&B[(size_t)(k0 + krow) * ldb + j0 + jc * 4];
            *(float4*)&sB[krow][jc * 4] = v;
        }
        __syncthreads();

        #pragma unroll
        for (int kk = 0; kk < 16; ++kk) {
            const float4 a4 = *(const float4*)&sA[kk][ti * 4];
            const float4 b4 = *(const float4*)&sB[kk][tj * 4];
            const float av[4] = {a4.x, a4.y, a4.z, a4.w};
            const float bv[4] = {b4.x, b4.y, b4.z, b4.w};
            #pragma unroll
            for (int ii = 0; ii < 4; ++ii)
                #pragma unroll
                for (int jjx = 0; jjx < 4; ++jjx)
                    acc[ii][jjx] = fmaf(av[ii], bv[jjx], acc[ii][jjx]);
        }
        __syncthreads();
    }

    #pragma unroll
    for (int ii = 0; ii < 4; ++ii) {
        const size_t crow = (size_t)(i0 + ti * 4 + ii) * ldc + j0 + tj * 4;
        #pragma unroll
        for (int jjx = 0; jjx < 4; ++jjx) {
            float v = acc[ii][jjx];
            if constexpr (BIAS) {
                const int col = j0 + tj * 4 + jjx;
                v += bias1[col] + bias2[col];
            }
            if constexpr (ADD_C) v += C[crow + jjx];
            C[crow + jjx] = v;
        }
    }
}

// ---------------------------------------------------------------------------
// Row softmax of T [M_DIM x L_SEQ], in place. One block per row. Unchanged.
// ---------------------------------------------------------------------------
__global__ __launch_bounds__(256) void softmax_rows(float* __restrict__ T) {
    __shared__ float red[8];
    const int m = blockIdx.x;
    const int tid = threadIdx.x;
    float* row = T + (size_t)m * L_SEQ;

    float4 v[4];
    #pragma unroll
    for (int c = 0; c < 4; ++c)
        v[c] = *(const float4*)&row[c * 1024 + tid * 4];

    float mx = -INFINITY;
    #pragma unroll
    for (int c = 0; c < 4; ++c)
        mx = fmaxf(mx, fmaxf(fmaxf(v[c].x, v[c].y), fmaxf(v[c].z, v[c].w)));
    #pragma unroll
    for (int o = 32; o; o >>= 1) mx = fmaxf(mx, __shfl_xor(mx, o));
    if ((tid & 63) == 0) red[tid >> 6] = mx;
    __syncthreads();
    mx = fmaxf(fmaxf(red[0], red[1]), fmaxf(red[2], red[3]));

    float sum = 0.0f;
    #pragma unroll
    for (int c = 0; c < 4; ++c) {
        v[c].x = expf(v[c].x - mx);
        v[c].y = expf(v[c].y - mx);
        v[c].z = expf(v[c].z - mx);
        v[c].w = expf(v[c].w - mx);
        sum += (v[c].x + v[c].y) + (v[c].z + v[c].w);
    }
    #pragma unroll
    for (int o = 32; o; o >>= 1) sum += __shfl_xor(sum, o);
    if ((tid & 63) == 0) red[4 + (tid >> 6)] = sum;
    __syncthreads();
    sum = (red[4] + red[5]) + (red[6] + red[7]);
    const float inv = 1.0f / sum;

    #pragma unroll
    for (int c = 0; c < 4; ++c) {
        v[c].x *= inv; v[c].y *= inv; v[c].z *= inv; v[c].w *= inv;
        *(float4*)&row[c * 1024 + tid * 4] = v[c];
    }
}

__global__ void copyA(const float* __restrict__ A, float* __restrict__ dst) {
    const int idx = blockIdx.x * 256 + threadIdx.x;
    ((float4*)dst)[idx] = ((const float4*)A)[idx];
}

// ---------------------------------------------------------------------------
// Persistent multi-workgroup LSTM — sentinel + packed-payload broadcast.
//
// 32 WGs x 256 threads. WG b owns h indices [b*16, b*16+16).
//   jj = wave*4 + ((lane>>4)&3) : local h index;  kg = lane&15 : k-slice.
// __launch_bounds__(256,1): 512-VGPR budget so the 128-VGPR weight array
// stays register-resident (R3's VGPR_Count=96 proved it was being re-loaded
// from L2 inside the loop under the default occupancy target).
//
// Broadcast protocol (hbuf = ull[2][32][8], 64 B/producer block):
//   word 0    : sentinel = step stamp (t+1), release-stored by tid 0 AFTER a
//               local __syncthreads (orders payload stores before it).
//   words 1..4: payload — 4 fp16 h values per word, relaxed-stored by lane 0
//               of each wave as soon as its 4 h values exist.
// Consumer side: ONLY wave 0 touches global — 32 lanes acquire-poll the 32
// sentinels (s_sleep backoff), then 64 lanes single-shot load the 128 payload
// words (zero retry variance) and fill sH[(t+1)&1].
// Overwrite safety (2-deep): producer reuses block at t+2 only after polling
// all sentinels of t+1; a WG publishes t+1 only after it consumed payload t.
// ---------------------------------------------------------------------------
__global__ __launch_bounds__(256, 1) void lstm_kernel(
    const float* __restrict__ Gm,     // [L_SEQ, G4] x-part + biases
    const float* __restrict__ W_hh,   // [G4, H_DIM]
    const float* __restrict__ h0,
    const float* __restrict__ c0,
    float* __restrict__ out,
    ull* hbuf) {                      // [2][32][8]

    __shared__ __align__(16) float sH[2][H_DIM];

    const int tid  = threadIdx.x;
    const int b    = blockIdx.x;
    const int lane = tid & 63;
    const int wave = tid >> 6;
    const int m    = (lane >> 4) & 3;
    const int jj   = wave * 4 + m;
    const int kg   = lane & 15;
    const int gj   = b * CHUNK + jj;          // global h index this thread serves

    // --- weights, rotated by kg: w[g][i] = W_hh[g*512+gj][kg*32 + ((i+kg)&7)*4 ..]
    float4 w[4][8];
    #pragma unroll
    for (int g = 0; g < 4; ++g) {
        const float* wrow = W_hh + (size_t)(g * H_DIM + gj) * H_DIM + kg * 32;
        #pragma unroll
        for (int i = 0; i < 8; ++i)
            w[g][i] = *(const float4*)&wrow[((i + kg) & 7) * 4];
    }

    // --- init h, c
    {
        const int i2 = tid * 2;
        sH[0][i2]     = h0[i2];
        sH[0][i2 + 1] = h0[i2 + 1];
    }
    float c = 0.0f;
    if (kg == 0) c = c0[gj];
    __syncthreads();

    // --- prefetch gate inputs for t=0
    float gin0 = 0.f, gin1 = 0.f, gin2 = 0.f, gin3 = 0.f;
    if (kg == 0) {
        const float* gp = Gm + gj;
        gin0 = gp[0 * H_DIM];
        gin1 = gp[1 * H_DIM];
        gin2 = gp[2 * H_DIM];
        gin3 = gp[3 * H_DIM];
    }

    for (int t = 0; t < L_SEQ; ++t) {
        const float4* sH4 = (const float4*)sH[t & 1];
        const size_t  par = (size_t)(t & 1) * 256;     // ull offset of this parity

        // prefetch gate inputs for t+1 (latency hides under this whole step)
        float nin0 = 0.f, nin1 = 0.f, nin2 = 0.f, nin3 = 0.f;
        if (kg == 0 && t + 1 < L_SEQ) {
            const float* gp = Gm + (size_t)(t + 1) * G4 + gj;
            nin0 = gp[0 * H_DIM];
            nin1 = gp[1 * H_DIM];
            nin2 = gp[2 * H_DIM];
            nin3 = gp[3 * H_DIM];
        }

        // partial dots: 4 gates x 32 k-floats
        float4 a0 = {0, 0, 0, 0}, a1 = {0, 0, 0, 0}, a2 = {0, 0, 0, 0}, a3 = {0, 0, 0, 0};
        #pragma unroll
        for (int i = 0; i < 8; ++i) {
            const float4 hv = sH4[kg * 8 + ((i + kg) & 7)];
            a0.x = fmaf(w[0][i].x, hv.x, a0.x); a0.y = fmaf(w[0][i].y, hv.y, a0.y);
            a0.z = fmaf(w[0][i].z, hv.z, a0.z); a0.w = fmaf(w[0][i].w, hv.w, a0.w);
            a1.x = fmaf(w[1][i].x, hv.x, a1.x); a1.y = fmaf(w[1][i].y, hv.y, a1.y);
            a1.z = fmaf(w[1][i].z, hv.z, a1.z); a1.w = fmaf(w[1][i].w, hv.w, a1.w);
            a2.x = fmaf(w[2][i].x, hv.x, a2.x); a2.y = fmaf(w[2][i].y, hv.y, a2.y);
            a2.z = fmaf(w[2][i].z, hv.z, a2.z); a2.w = fmaf(w[2][i].w, hv.w, a2.w);
            a3.x = fmaf(w[3][i].x, hv.x, a3.x); a3.y = fmaf(w[3][i].y, hv.y, a3.y);
            a3.z = fmaf(w[3][i].z, hv.z, a3.z); a3.w = fmaf(w[3][i].w, hv.w, a3.w);
        }
        float s0 = (a0.x + a0.y) + (a0.z + a0.w);
        float s1 = (a1.x + a1.y) + (a1.z + a1.w);
        float s2 = (a2.x + a2.y) + (a2.z + a2.w);
        float s3 = (a3.x + a3.y) + (a3.z + a3.w);
        #pragma unroll
        for (int msk = 1; msk <= 8; msk <<= 1) {
            s0 += __shfl_xor(s0, msk);
            s1 += __shfl_xor(s1, msk);
            s2 += __shfl_xor(s2, msk);
            s3 += __shfl_xor(s3, msk);
        }

        float h = 0.0f;
        if (kg == 0) {
            const float i_ = fast_sigmoid(s0 + gin0);
            const float f_ = fast_sigmoid(s1 + gin1);
            const float g_ = fast_tanh(s2 + gin2);
            const float o_ = fast_sigmoid(s3 + gin3);
            c = f_ * c + i_ * g_;
            h = o_ * fast_tanh(c);
        }

        // publish payload (this wave's 4 h values -> one fully-packed word)
        if (t + 1 < L_SEQ) {
            const float hA = __shfl(h, 0);
            const float hB = __shfl(h, 16);
            const float hC = __shfl(h, 32);
            const float hD = __shfl(h, 48);
            if (lane == 0) {
                const __half2 lo2 = __floats2half2_rn(hA, hB);
                const __half2 hi2 = __floats2half2_rn(hC, hD);
                const unsigned lo = __builtin_bit_cast(unsigned, lo2);
                const unsigned hi = __builtin_bit_cast(unsigned, hi2);
                const ull word = ((ull)hi << 32) | (ull)lo;
                __hip_atomic_store(&hbuf[par + b * 8 + 1 + wave], word,
                                   __ATOMIC_RELAXED, __HIP_MEMORY_SCOPE_AGENT);
            }
        }
        if (kg == 0) {
            out[OUT_Y + (size_t)t * H_DIM + gj] = h;
            if (t == L_SEQ - 1) {
                out[OUT_HT + gj] = h;
                out[OUT_CT + gj] = c;
                out[OUT_A + (size_t)M_DIM * H_DIM + gj] = h;   // A_new last row
            }
        }
        gin0 = nin0; gin1 = nin1; gin2 = nin2; gin3 = nin3;

        __syncthreads();   // drains payload stores (vmcnt 0) before sentinel

        if (t + 1 < L_SEQ) {
            if (tid == 0) {
                __hip_atomic_store(&hbuf[par + b * 8], (ull)(unsigned)(t + 1),
                                   __ATOMIC_RELEASE, __HIP_MEMORY_SCOPE_AGENT);
            }
            if (tid < 64) {
                if (lane < 32) {
                    const ull want = (ull)(unsigned)(t + 1);
                    for (;;) {
                        const ull v = __hip_atomic_load(&hbuf[par + lane * 8],
                                                        __ATOMIC_ACQUIRE,
                                                        __HIP_MEMORY_SCOPE_AGENT);
                        if (v == want) break;
                        __builtin_amdgcn_s_sleep(1);
                    }
                }
                // single-shot payload read: 128 words, 2 per lane
                float* dst = sH[(t + 1) & 1];
                #pragma unroll
                for (int rep = 0; rep < 2; ++rep) {
                    const int g = lane + rep * 64;           // 4-group index 0..127
                    const int p = g >> 2, wv = g & 3;
                    const ull v = __hip_atomic_load(&hbuf[par + p * 8 + 1 + wv],
                                                    __ATOMIC_RELAXED,
                                                    __HIP_MEMORY_SCOPE_AGENT);
                    const __half2 lo2 = __builtin_bit_cast(__half2, (unsigned)v);
                    const __half2 hi2 = __builtin_bit_cast(__half2, (unsigned)(v >> 32));
                    const float2 f01 = __half22float2(lo2);
                    const float2 f23 = __half22float2(hi2);
                    *(float4*)&dst[4 * g] = make_float4(f01.x, f01.y, f23.x, f23.y);
                }
            }
        }
        __syncthreads();
    }
}

// ---------------------------------------------------------------------------
extern "C" void kernel_launch(void* const* d_in, const int* in_sizes, int n_in,
                              void* d_out, int out_size, void* d_ws, size_t ws_size,
                              hipStream_t stream) {
    const int*   sent  = (const int*)d_in[0];
    const float* h0    = (const float*)d_in[1];
    const float* c0    = (const float*)d_in[2];
    const float* A     = (const float*)d_in[3];
    const float* embed = (const float*)d_in[4];
    const float* W_ih  = (const float*)d_in[5];
    const float* W_hh  = (const float*)d_in[6];
    const float* b_ih  = (const float*)d_in[7];
    const float* b_hh  = (const float*)d_in[8];
    float* out = (float*)d_out;

    float* ws = (float*)d_ws;
    float* x    = ws;                                  // L*H       (8 MB)
    float* T    = x + (size_t)L_SEQ * H_DIM;           // M*L       (16 MB)
    float* Gm   = T + (size_t)M_DIM * L_SEQ;           // L*4H      (32 MB)
    ull*   hbuf = (ull*)(Gm + (size_t)L_SEQ * G4);     // 2*32*8 u64 (4 KB)
    // 0xAA poison in hbuf: sentinel 0xAAAA.. never equals a stamp (<= 4096).

    // x = embed[sent]
    gather_embed<<<L_SEQ, 128, 0, stream>>>(sent, embed, x);

    // T = A @ x^T   [M, L], K = H
    gemm_tile<false, true, false, false><<<dim3(L_SEQ / 64, M_DIM / 64), 256, 0, stream>>>(
        A, H_DIM, x, H_DIM, T, L_SEQ, H_DIM, nullptr, nullptr);

    // row softmax over L
    softmax_rows<<<M_DIM, 256, 0, stream>>>(T);

    // x += T^T @ A   [L, H], K = M
    gemm_tile<true, false, true, false><<<dim3(H_DIM / 64, L_SEQ / 64), 256, 0, stream>>>(
        T, L_SEQ, A, H_DIM, x, H_DIM, M_DIM, nullptr, nullptr);

    // G = x @ W_ih^T + b_ih + b_hh   [L, 4H], K = H
    gemm_tile<false, true, false, true><<<dim3(G4 / 64, L_SEQ / 64), 256, 0, stream>>>(
        x, H_DIM, W_ih, H_DIM, Gm, G4, H_DIM, b_ih, b_hh);

    // A_new rows 0..M-1
    copyA<<<(M_DIM * H_DIM / 4) / 256, 256, 0, stream>>>(A, out + OUT_A);

    // sequential LSTM over L steps (sentinel + packed payload broadcast)
    lstm_kernel<<<N_WG, 256, 0, stream>>>(Gm, W_hh, h0, c0, out, hbuf);
}

// Round 5
// 10483.794 us; speedup vs baseline: 1.2813x; 1.2813x over previous
//
#include <hip/hip_runtime.h>
#include <hip/hip_fp16.h>
#include <math.h>

#define L_SEQ 4096
#define H_DIM 512
#define M_DIM 1024
#define G4    2048   // 4*H
#define N_WG  32
#define CHUNK 16     // h indices per workgroup

#define OUT_HT 0
#define OUT_CT 512
#define OUT_Y  1024
#define OUT_A  (1024 + L_SEQ*H_DIM)   // 2098176

typedef unsigned long long ull;

__device__ __forceinline__ float fast_sigmoid(float v) {
    return 1.0f / (1.0f + __expf(-v));
}
__device__ __forceinline__ float fast_tanh(float v) {
    const float ax = fabsf(v);
    const float e = __expf(2.0f * ax);          // inf for large ax -> r = 1
    const float r = 1.0f - 2.0f / (e + 1.0f);
    return copysignf(r, v);
}

// Opaque 16B load: the asm result cannot be rematerialized, so the value MUST
// stay register-resident across the whole time loop (the compiler was sinking
// ordinary invariant loads back into the loop -> 128 KB/CU/step L2 streaming).
__device__ __forceinline__ float4 ld_f4_pin(const float* p) {
    float4 r;
    asm volatile("global_load_dwordx4 %0, %1, off\n\ts_waitcnt vmcnt(0)"
                 : "=v"(r) : "v"(p));
    return r;
}

// ---------------------------------------------------------------------------
// x[l, :] = embed[sent[l], :]
// ---------------------------------------------------------------------------
__global__ void gather_embed(const int* __restrict__ sent,
                             const float* __restrict__ embed,
                             float* __restrict__ x) {
    const int l = blockIdx.x;
    const int t = threadIdx.x;          // 128 threads, float4 each
    const int row = sent[l];
    const float4 v = *(const float4*)&embed[(size_t)row * H_DIM + t * 4];
    *(float4*)&x[(size_t)l * H_DIM + t * 4] = v;
}

// ---------------------------------------------------------------------------
// Generic fp32 tile GEMM (64x64 tile, BK=16, 256 thr, 4x4 micro) — unchanged.
// ---------------------------------------------------------------------------
template<bool AT, bool BT, bool ADD_C, bool BIAS>
__global__ __launch_bounds__(256) void gemm_tile(
    const float* __restrict__ A, int lda,
    const float* __restrict__ B, int ldb,
    float* __restrict__ C, int ldc,
    int K,
    const float* __restrict__ bias1,
    const float* __restrict__ bias2) {

    __shared__ float sA[16][68];
    __shared__ float sB[16][68];

    const int tid = threadIdx.x;
    const int i0 = blockIdx.y * 64;
    const int j0 = blockIdx.x * 64;
    const int ti = tid & 15;
    const int tj = tid >> 4;

    float acc[4][4] = {};

    for (int k0 = 0; k0 < K; k0 += 16) {
        if (!AT) {
            const int row = tid >> 2, kq = tid & 3;
            const float4 v = *(const float4*)&A[(size_t)(i0 + row) * lda + k0 + kq * 4];
            sA[kq * 4 + 0][row] = v.x;
            sA[kq * 4 + 1][row] = v.y;
            sA[kq * 4 + 2][row] = v.z;
            sA[kq * 4 + 3][row] = v.w;
        } else {
            const int krow = tid >> 4, ic = tid & 15;
            const float4 v = *(const float4*)&A[(size_t)(k0 + krow) * lda + i0 + ic * 4];
            *(float4*)&sA[krow][ic * 4] = v;
        }
        if (BT) {
            const int row = tid >> 2, kq = tid & 3;
            const float4 v = *(const float4*)&B[(size_t)(j0 + row) * ldb + k0 + kq * 4];
            sB[kq * 4 + 0][row] = v.x;
            sB[kq * 4 + 1][row] = v.y;
            sB[kq * 4 + 2][row] = v.z;
            sB[kq * 4 + 3][row] = v.w;
        } else {
            const int krow = tid >> 4, jc = tid & 15;
            const float4 v = *(const float4*)&B[(size_t)(k0 + krow) * ldb + j0 + jc * 4];
            *(float4*)&sB[krow][jc * 4] = v;
        }
        __syncthreads();

        #pragma unroll
        for (int kk = 0; kk < 16; ++kk) {
            const float4 a4 = *(const float4*)&sA[kk][ti * 4];
            const float4 b4 = *(const float4*)&sB[kk][tj * 4];
            const float av[4] = {a4.x, a4.y, a4.z, a4.w};
            const float bv[4] = {b4.x, b4.y, b4.z, b4.w};
            #pragma unroll
            for (int ii = 0; ii < 4; ++ii)
                #pragma unroll
                for (int jjx = 0; jjx < 4; ++jjx)
                    acc[ii][jjx] = fmaf(av[ii], bv[jjx], acc[ii][jjx]);
        }
        __syncthreads();
    }

    #pragma unroll
    for (int ii = 0; ii < 4; ++ii) {
        const size_t crow = (size_t)(i0 + ti * 4 + ii) * ldc + j0 + tj * 4;
        #pragma unroll
        for (int jjx = 0; jjx < 4; ++jjx) {
            float v = acc[ii][jjx];
            if constexpr (BIAS) {
                const int col = j0 + tj * 4 + jjx;
                v += bias1[col] + bias2[col];
            }
            if constexpr (ADD_C) v += C[crow + jjx];
            C[crow + jjx] = v;
        }
    }
}

// ---------------------------------------------------------------------------
// Row softmax of T [M_DIM x L_SEQ], in place. One block per row. Unchanged.
// ---------------------------------------------------------------------------
__global__ __launch_bounds__(256) void softmax_rows(float* __restrict__ T) {
    __shared__ float red[8];
    const int m = blockIdx.x;
    const int tid = threadIdx.x;
    float* row = T + (size_t)m * L_SEQ;

    float4 v[4];
    #pragma unroll
    for (int c = 0; c < 4; ++c)
        v[c] = *(const float4*)&row[c * 1024 + tid * 4];

    float mx = -INFINITY;
    #pragma unroll
    for (int c = 0; c < 4; ++c)
        mx = fmaxf(mx, fmaxf(fmaxf(v[c].x, v[c].y), fmaxf(v[c].z, v[c].w)));
    #pragma unroll
    for (int o = 32; o; o >>= 1) mx = fmaxf(mx, __shfl_xor(mx, o));
    if ((tid & 63) == 0) red[tid >> 6] = mx;
    __syncthreads();
    mx = fmaxf(fmaxf(red[0], red[1]), fmaxf(red[2], red[3]));

    float sum = 0.0f;
    #pragma unroll
    for (int c = 0; c < 4; ++c) {
        v[c].x = expf(v[c].x - mx);
        v[c].y = expf(v[c].y - mx);
        v[c].z = expf(v[c].z - mx);
        v[c].w = expf(v[c].w - mx);
        sum += (v[c].x + v[c].y) + (v[c].z + v[c].w);
    }
    #pragma unroll
    for (int o = 32; o; o >>= 1) sum += __shfl_xor(sum, o);
    if ((tid & 63) == 0) red[4 + (tid >> 6)] = sum;
    __syncthreads();
    sum = (red[4] + red[5]) + (red[6] + red[7]);
    const float inv = 1.0f / sum;

    #pragma unroll
    for (int c = 0; c < 4; ++c) {
        v[c].x *= inv; v[c].y *= inv; v[c].z *= inv; v[c].w *= inv;
        *(float4*)&row[c * 1024 + tid * 4] = v[c];
    }
}

__global__ void copyA(const float* __restrict__ A, float* __restrict__ dst) {
    const int idx = blockIdx.x * 256 + threadIdx.x;
    ((float4*)dst)[idx] = ((const float4*)A)[idx];
}

// ---------------------------------------------------------------------------
// Persistent multi-workgroup LSTM, fp16-pair stamped broadcast (R3 protocol)
// + pinned-in-VGPR weights (inline-asm loads, launch_bounds(256,1)).
//
// 32 WGs x 256 threads. WG b owns h indices [b*16, b*16+16).
//   jj = wave*4 + ((lane>>4)&3) : local h index;  kg = lane&15 : k-slice.
// Broadcast: hbuf[t&1][256] u64 words; word j = stamp(t+1)<<32 | fp16(h[2j+1])
// <<16 | fp16(h[2j]). One relaxed agent-scope atomic store per word; each
// reader thread polls exactly ONE word (stamp+data arrive together — single
// parallel RT). Double-buffered sH -> one barrier per step. Gm gate inputs
// prefetched one step ahead. 2-deep hbuf overwrite-safe: a WG reaches step
// t+2 only after polling all of t+1, whose writers completed their t-polls.
// ---------------------------------------------------------------------------
__global__ __launch_bounds__(256, 1) void lstm_kernel(
    const float* __restrict__ Gm,     // [L_SEQ, G4] x-part + biases
    const float* __restrict__ W_hh,   // [G4, H_DIM]
    const float* __restrict__ h0,
    const float* __restrict__ c0,
    float* __restrict__ out,
    ull* hbuf) {                      // [2][256] stamped fp16-pair words

    __shared__ __align__(16) float sH[2][H_DIM];

    const int tid  = threadIdx.x;
    const int b    = blockIdx.x;
    const int lane = tid & 63;
    const int wave = tid >> 6;
    const int m    = (lane >> 4) & 3;
    const int jj   = wave * 4 + m;
    const int kg   = lane & 15;
    const int gj   = b * CHUNK + jj;          // global h index this thread serves

    // --- weights, rotated by kg, PINNED in VGPRs via opaque asm loads
    float4 w[4][8];
    #pragma unroll
    for (int g = 0; g < 4; ++g) {
        const float* wrow = W_hh + (size_t)(g * H_DIM + gj) * H_DIM + kg * 32;
        #pragma unroll
        for (int i = 0; i < 8; ++i)
            w[g][i] = ld_f4_pin(&wrow[((i + kg) & 7) * 4]);
    }

    // --- init h, c
    {
        const int i2 = tid * 2;
        sH[0][i2]     = h0[i2];
        sH[0][i2 + 1] = h0[i2 + 1];
    }
    float c = 0.0f;
    if (kg == 0) c = c0[gj];
    __syncthreads();

    // --- prefetch gate inputs for t=0
    float gin0 = 0.f, gin1 = 0.f, gin2 = 0.f, gin3 = 0.f;
    if (kg == 0) {
        const float* gp = Gm + gj;
        gin0 = gp[0 * H_DIM];
        gin1 = gp[1 * H_DIM];
        gin2 = gp[2 * H_DIM];
        gin3 = gp[3 * H_DIM];
    }

    for (int t = 0; t < L_SEQ; ++t) {
        const float4* sH4 = (const float4*)sH[t & 1];

        // prefetch gate inputs for t+1 (latency hides under this whole step)
        float nin0 = 0.f, nin1 = 0.f, nin2 = 0.f, nin3 = 0.f;
        if (kg == 0 && t + 1 < L_SEQ) {
            const float* gp = Gm + (size_t)(t + 1) * G4 + gj;
            nin0 = gp[0 * H_DIM];
            nin1 = gp[1 * H_DIM];
            nin2 = gp[2 * H_DIM];
            nin3 = gp[3 * H_DIM];
        }

        // partial dots: 4 gates x 32 k-floats
        float4 a0 = {0, 0, 0, 0}, a1 = {0, 0, 0, 0}, a2 = {0, 0, 0, 0}, a3 = {0, 0, 0, 0};
        #pragma unroll
        for (int i = 0; i < 8; ++i) {
            const float4 hv = sH4[kg * 8 + ((i + kg) & 7)];
            a0.x = fmaf(w[0][i].x, hv.x, a0.x); a0.y = fmaf(w[0][i].y, hv.y, a0.y);
            a0.z = fmaf(w[0][i].z, hv.z, a0.z); a0.w = fmaf(w[0][i].w, hv.w, a0.w);
            a1.x = fmaf(w[1][i].x, hv.x, a1.x); a1.y = fmaf(w[1][i].y, hv.y, a1.y);
            a1.z = fmaf(w[1][i].z, hv.z, a1.z); a1.w = fmaf(w[1][i].w, hv.w, a1.w);
            a2.x = fmaf(w[2][i].x, hv.x, a2.x); a2.y = fmaf(w[2][i].y, hv.y, a2.y);
            a2.z = fmaf(w[2][i].z, hv.z, a2.z); a2.w = fmaf(w[2][i].w, hv.w, a2.w);
            a3.x = fmaf(w[3][i].x, hv.x, a3.x); a3.y = fmaf(w[3][i].y, hv.y, a3.y);
            a3.z = fmaf(w[3][i].z, hv.z, a3.z); a3.w = fmaf(w[3][i].w, hv.w, a3.w);
        }
        float s0 = (a0.x + a0.y) + (a0.z + a0.w);
        float s1 = (a1.x + a1.y) + (a1.z + a1.w);
        float s2 = (a2.x + a2.y) + (a2.z + a2.w);
        float s3 = (a3.x + a3.y) + (a3.z + a3.w);
        #pragma unroll
        for (int msk = 1; msk <= 8; msk <<= 1) {
            s0 += __shfl_xor(s0, msk);
            s1 += __shfl_xor(s1, msk);
            s2 += __shfl_xor(s2, msk);
            s3 += __shfl_xor(s3, msk);
        }

        if (kg == 0) {
            const float i_ = fast_sigmoid(s0 + gin0);
            const float f_ = fast_sigmoid(s1 + gin1);
            const float g_ = fast_tanh(s2 + gin2);
            const float o_ = fast_sigmoid(s3 + gin3);
            c = f_ * c + i_ * g_;
            const float h = o_ * fast_tanh(c);
            // pair up: even-jj lane gets odd-jj partner's h (lane 0<-16, 32<-48)
            const float hp = __shfl_xor(h, 16);
            if ((m & 1) == 0) {
                const __half2 p2 = __floats2half2_rn(h, hp);   // lo = even jj
                const unsigned bits = __builtin_bit_cast(unsigned, p2);
                const ull pack = ((ull)(unsigned)(t + 1) << 32) | (ull)bits;
                __hip_atomic_store(&hbuf[(t & 1) * 256 + (gj >> 1)], pack,
                                   __ATOMIC_RELAXED, __HIP_MEMORY_SCOPE_AGENT);
            }
            out[OUT_Y + (size_t)t * H_DIM + gj] = h;
            if (t == L_SEQ - 1) {
                out[OUT_HT + gj] = h;
                out[OUT_CT + gj] = c;
                out[OUT_A + (size_t)M_DIM * H_DIM + gj] = h;   // A_new last row
            }
        }
        gin0 = nin0; gin1 = nin1; gin2 = nin2; gin3 = nin3;

        if (t + 1 < L_SEQ) {
            // each thread polls exactly one stamped word (one parallel RT)
            const unsigned want = (unsigned)(t + 1);
            ull v;
            do {
                v = __hip_atomic_load(&hbuf[(t & 1) * 256 + tid],
                                      __ATOMIC_RELAXED, __HIP_MEMORY_SCOPE_AGENT);
            } while ((unsigned)(v >> 32) != want);
            const __half2 p2 = __builtin_bit_cast(__half2, (unsigned)v);
            const float2 f2 = __half22float2(p2);
            float* dst = sH[(t + 1) & 1];
            dst[tid * 2]     = f2.x;
            dst[tid * 2 + 1] = f2.y;
        }
        __syncthreads();
    }
}

// ---------------------------------------------------------------------------
extern "C" void kernel_launch(void* const* d_in, const int* in_sizes, int n_in,
                              void* d_out, int out_size, void* d_ws, size_t ws_size,
                              hipStream_t stream) {
    const int*   sent  = (const int*)d_in[0];
    const float* h0    = (const float*)d_in[1];
    const float* c0    = (const float*)d_in[2];
    const float* A     = (const float*)d_in[3];
    const float* embed = (const float*)d_in[4];
    const float* W_ih  = (const float*)d_in[5];
    const float* W_hh  = (const float*)d_in[6];
    const float* b_ih  = (const float*)d_in[7];
    const float* b_hh  = (const float*)d_in[8];
    float* out = (float*)d_out;

    float* ws = (float*)d_ws;
    float* x    = ws;                                  // L*H       (8 MB)
    float* T    = x + (size_t)L_SEQ * H_DIM;           // M*L       (16 MB)
    float* Gm   = T + (size_t)M_DIM * L_SEQ;           // L*4H      (32 MB)
    ull*   hbuf = (ull*)(Gm + (size_t)L_SEQ * G4);     // 2*256 u64
    // 0xAA poison in hbuf: stamp 0xAAAAAAAA never equals a wanted stamp.

    // x = embed[sent]
    gather_embed<<<L_SEQ, 128, 0, stream>>>(sent, embed, x);

    // T = A @ x^T   [M, L], K = H
    gemm_tile<false, true, false, false><<<dim3(L_SEQ / 64, M_DIM / 64), 256, 0, stream>>>(
        A, H_DIM, x, H_DIM, T, L_SEQ, H_DIM, nullptr, nullptr);

    // row softmax over L
    softmax_rows<<<M_DIM, 256, 0, stream>>>(T);

    // x += T^T @ A   [L, H], K = M
    gemm_tile<true, false, true, false><<<dim3(H_DIM / 64, L_SEQ / 64), 256, 0, stream>>>(
        T, L_SEQ, A, H_DIM, x, H_DIM, M_DIM, nullptr, nullptr);

    // G = x @ W_ih^T + b_ih + b_hh   [L, 4H], K = H
    gemm_tile<false, true, false, true><<<dim3(G4 / 64, L_SEQ / 64), 256, 0, stream>>>(
        x, H_DIM, W_ih, H_DIM, Gm, G4, H_DIM, b_ih, b_hh);

    // A_new rows 0..M-1
    copyA<<<(M_DIM * H_DIM / 4) / 256, 256, 0, stream>>>(A, out + OUT_A);

    // sequential LSTM over L steps (fp16-pair stamped broadcast, pinned weights)
    lstm_kernel<<<N_WG, 256, 0, stream>>>(Gm, W_hh, h0, c0, out, hbuf);
}